// Round 11
// baseline (341.527 us; speedup 1.0000x reference)
//
#include <hip/hip_runtime.h>
#include <hip/hip_fp16.h>
#include <math.h>
#include <string.h>

#define B_SZ  8192
#define KD    256
#define NCLS  32
#define NT    64                // 128-row panels per dim
#define NBLK  520               // 512 strip blocks + 8 d32 blocks
#define SQRT_INVT 3.16227766016838f   // sqrt(10): fold 1/T into normalized rows
#define SCJ      0.0625f        // fp16 store scale for j-side partials
#define SCJ_INV  16.0f

typedef __attribute__((ext_vector_type(8))) short short8;
typedef __attribute__((ext_vector_type(4))) float f32x4;

static __device__ __forceinline__ unsigned short f2bf(float f) {
    unsigned u = __float_as_uint(f);
    return (unsigned short)((u + 0x7FFF + ((u >> 16) & 1)) >> 16);   // RNE
}
static __device__ __forceinline__ float bf2f(unsigned short h) {
    return __uint_as_float((unsigned)h << 16);
}

// ---------------- kernel 1: normalize+scale rows, emit combined [hi(256)|lo(256)] bf16 ----------------
__global__ void prep_kernel(const float* __restrict__ feat, unsigned short* __restrict__ Fhl) {
    int row  = blockIdx.x * 4 + (threadIdx.x >> 6);
    int lane = threadIdx.x & 63;
    const float4 v = ((const float4*)(feat + (size_t)row * KD))[lane];
    float s = v.x * v.x + v.y * v.y + v.z * v.z + v.w * v.w;
    #pragma unroll
    for (int off = 1; off < 64; off <<= 1) s += __shfl_xor(s, off, 64);
    float rn = rsqrtf(s) * SQRT_INVT;
    float fn[4] = {v.x * rn, v.y * rn, v.z * rn, v.w * rn};
    ushort4 hi, lo;
    unsigned short* hp = (unsigned short*)&hi;
    unsigned short* lp = (unsigned short*)&lo;
    #pragma unroll
    for (int e = 0; e < 4; e++) {
        unsigned short h = f2bf(fn[e]);
        hp[e] = h;
        lp[e] = f2bf(fn[e] - bf2f(h));
    }
    ((ushort4*)(Fhl + (size_t)row * 512))[lane]       = hi;   // cols 0..255  = hi
    ((ushort4*)(Fhl + (size_t)row * 512 + 256))[lane] = lo;   // cols 256..511 = lo
}

// ---------------- kernel 2: global per-class counts ----------------
__global__ void count_kernel(const int* __restrict__ labels, int* __restrict__ counts) {
    __shared__ int sc[NCLS];
    int t = threadIdx.x;
    if (t < NCLS) sc[t] = 0;
    __syncthreads();
    for (int i = t; i < B_SZ; i += 256) atomicAdd(&sc[labels[i]], 1);
    __syncthreads();
    if (t < NCLS) counts[t] = sc[t];
}

// ---------------- kernel 3: triangle sim GEMM (diagonal-offset strips) + two-sided MFMA class reduce ----------------
// Strip block (it, s): 4 tiles d = s*4+k, jt = (it+d)%64. i-side accumulates across strip (1 fp32 dump);
// j-side dumped per tile (fp16). d32 blocks: 4 tiles (it=g*4+k, it+32), per-tile i-dumps.
// Cross-wave partial halves combined via scr LDS reduce BEFORE every dump (R10 bug: last-writer-wins race).
__global__ __launch_bounds__(256, 2) void sim_kernel(
    const unsigned short* __restrict__ Fhl, const int* __restrict__ labels,
    float* __restrict__ ipart, unsigned int* __restrict__ jpart,
    float* __restrict__ ipos, float* __restrict__ jpos)
{
    __shared__ __align__(16) unsigned short sbuf[2][2][128 * 64];  // 64KB: [buf][A/B]
    __shared__ int   slab_i[128], slab_j[128];
    __shared__ float spos_i[128], spos_j[128];

    const int bid = blockIdx.x;
    const int swz = (bid & 7) * (NBLK / 8) + (bid >> 3);   // bijective XCD swizzle (520 % 8 == 0)
    const bool isStrip = (swz < 512);
    const int it_b = swz >> 3;        // strip: fixed i-panel
    const int s_b  = swz & 7;         // strip index
    const int g_b  = swz - 512;       // d32 group

    const int t    = threadIdx.x;
    const int wave = t >> 6;
    const int lane = t & 63;
    const int wr   = wave >> 1;       // 0..1 -> 64-row (i) half
    const int wc   = wave & 1;        // 0..1 -> 64-col (j) half
    const int l15  = lane & 15;
    const int l4   = lane >> 4;

    const int rT = t >> 3;    // row-within-32 staged per quarter
    const int s8 = t & 7;     // physical 16B slot

    auto STAGE = [&](int buf, int i0s, int j0s, int kc) {
        #pragma unroll
        for (int a = 0; a < 4; ++a) {
            int r   = a * 32 + rT;
            int sl  = s8 ^ (r & 7);                         // logical slot (involution)
            int col = kc + (sl & 3) * 8 + ((sl & 4) << 6);  // slots 0-3 hi, 4-7 lo (+256)
            const unsigned short* gA = Fhl + (size_t)(i0s + r) * 512 + col;
            char* lA = (char*)&sbuf[buf][0][0] + a * 4096 + wave * 1024;
            __builtin_amdgcn_global_load_lds(
                (const __attribute__((address_space(1))) void*)gA,
                (__attribute__((address_space(3))) void*)lA, 16, 0, 0);
            const unsigned short* gB = Fhl + (size_t)(j0s + r) * 512 + col;
            char* lB = (char*)&sbuf[buf][1][0] + a * 4096 + wave * 1024;
            __builtin_amdgcn_global_load_lds(
                (const __attribute__((address_space(1))) void*)gB,
                (__attribute__((address_space(3))) void*)lB, 16, 0, 0);
        }
    };

    // persistent i-side class sums (strip: across 4 tiles)
    f32x4 cs_i[4][2];
    #pragma unroll
    for (int m = 0; m < 4; m++)
        #pragma unroll
        for (int cb = 0; cb < 2; cb++)
            cs_i[m][cb] = (f32x4){0.f, 0.f, 0.f, 0.f};
    if (t < 128) spos_i[t] = 0.0f;

    int labi[4];

    #pragma unroll 1
    for (int k = 0; k < 4; ++k) {
        const int it_t = isStrip ? it_b : g_b * 4 + k;
        const int d    = isStrip ? s_b * 4 + k : 32;
        const int jt_t = (it_t + d) & 63;
        const bool diag = (d == 0);
        const int i0 = it_t * 128;
        const int j0 = jt_t * 128;

        if (t < 128) { slab_j[t] = labels[j0 + t]; spos_j[t] = 0.0f; }
        if (k == 0 || !isStrip) {
            if (t < 128) slab_i[t] = labels[i0 + t];
            #pragma unroll
            for (int m = 0; m < 4; m++) labi[m] = labels[i0 + wr * 64 + m * 16 + l15];
        }

        f32x4 acc[4][4];
        #pragma unroll
        for (int m = 0; m < 4; m++)
            #pragma unroll
            for (int n = 0; n < 4; n++)
                acc[m][n] = (f32x4){0.f, 0.f, 0.f, 0.f};

        STAGE(0, i0, j0, 0);
        __syncthreads();                    // stage0 landed + slabs/clears visible

        // ---- 2-phase pipelined K-loop: 8 steps of BK=32, 3 products ----
        #pragma unroll 1
        for (int ks = 0; ks < 8; ++ks) {
            if (ks < 7) STAGE((ks + 1) & 1, i0, j0, (ks + 1) * 32);
            const unsigned short* pA = &sbuf[ks & 1][0][0];
            const unsigned short* pB = &sbuf[ks & 1][1][0];
            short8 bh[4], bl[4];
            #pragma unroll
            for (int n = 0; n < 4; ++n) {
                int r = wc * 64 + n * 16 + l15;
                bh[n] = *(const short8*)&pB[r * 64 + ((l4 ^ (r & 7)) * 8)];
                bl[n] = *(const short8*)&pB[r * 64 + (((4 + l4) ^ (r & 7)) * 8)];
            }
            __builtin_amdgcn_s_setprio(1);
            #pragma unroll
            for (int m = 0; m < 4; ++m) {
                int r = wr * 64 + m * 16 + l15;
                short8 ah = *(const short8*)&pA[r * 64 + ((l4 ^ (r & 7)) * 8)];
                short8 al = *(const short8*)&pA[r * 64 + (((4 + l4) ^ (r & 7)) * 8)];
                #pragma unroll
                for (int n = 0; n < 4; ++n) {
                    // swapped operands: q indexes j. products: BhAh + BhAl + BlAh
                    acc[m][n] = __builtin_amdgcn_mfma_f32_16x16x32_bf16(bh[n], ah, acc[m][n], 0, 0, 0);
                    acc[m][n] = __builtin_amdgcn_mfma_f32_16x16x32_bf16(bh[n], al, acc[m][n], 0, 0, 0);
                    acc[m][n] = __builtin_amdgcn_mfma_f32_16x16x32_bf16(bl[n], ah, acc[m][n], 0, 0, 0);
                }
            }
            __builtin_amdgcn_s_setprio(0);
            __syncthreads();   // drains next stage; swaps buffers
        }

        // ---- epilogue: sim -> spos (LDS atomics, rare) + E=exp ----
        #pragma unroll
        for (int m = 0; m < 4; m++) {
            const int il = wr * 64 + m * 16 + l15;
            #pragma unroll
            for (int n = 0; n < 4; n++) {
                const int jb = wc * 64 + n * 16 + l4 * 4;
                int4 lj = *(const int4*)&slab_j[jb];
                const int* ljp = (const int*)&lj;
                #pragma unroll
                for (int q = 0; q < 4; q++) {
                    const int jl = jb + q;
                    float sim = acc[m][n][q];            // already scaled by 1/T
                    bool self = diag && (il == jl);
                    if (!self && ljp[q] == labi[m]) {
                        atomicAdd(&spos_i[il], sim);
                        if (!diag) atomicAdd(&spos_j[jl], sim);
                    }
                    acc[m][n][q] = self ? 0.0f : __expf(sim);
                }
            }
        }

        // one-hot fragments: hf_j (j labels) always; hf_i (i labels) for off-diag
        short8 hf_j[2][2], hf_i[2][2];
        #pragma unroll
        for (int kk = 0; kk < 2; kk++) {
            const int jb = wc * 64 + kk * 32 + l4 * 8;
            const int ib = wr * 64 + kk * 32 + l4 * 8;
            #pragma unroll
            for (int cb = 0; cb < 2; cb++) {
                short8 hj, hi;
                #pragma unroll
                for (int e = 0; e < 8; e++) {
                    hj[e] = (slab_j[jb + e] == cb * 16 + l15) ? (short)0x3F80 : (short)0;
                    hi[e] = (slab_i[ib + e] == cb * 16 + l15) ? (short)0x3F80 : (short)0;
                }
                hf_j[kk][cb] = hj;
                hf_i[kk][cb] = hi;
            }
        }

        char* sE = (char*)&sbuf[1][0][0];    // 32KB: [128][256B] bf16, XOR-swizzled rows
        float* scr = (float*)&sbuf[0][0][0]; // cross-wave combine scratch [128][33] f32

        // ---- i-side: E rows=i -> accumulate cs_i (this wave: j in wc-half only) ----
        #pragma unroll
        for (int copy = 0; copy < 2; copy++) {
            #pragma unroll
            for (int m = 0; m < 4; m++) {
                const int row = wr * 64 + m * 16 + l15;
                #pragma unroll
                for (int n = 0; n < 4; n++) {
                    const int bc = (wc * 128 + n * 32 + l4 * 8) ^ ((row & 7) << 4);
                    unsigned short b[4];
                    #pragma unroll
                    for (int q = 0; q < 4; q++) {
                        float e = acc[m][n][q];
                        unsigned short h = f2bf(e);
                        b[q] = copy == 0 ? h : f2bf(e - bf2f(h));
                    }
                    uint2 w;
                    w.x = (unsigned)b[0] | ((unsigned)b[1] << 16);
                    w.y = (unsigned)b[2] | ((unsigned)b[3] << 16);
                    *(uint2*)(sE + (size_t)row * 256 + bc) = w;
                }
            }
            #pragma unroll
            for (int m = 0; m < 4; m++) {
                const int row = wr * 64 + m * 16 + l15;
                #pragma unroll
                for (int kk = 0; kk < 2; kk++) {
                    const int bc = (wc * 128 + kk * 64 + l4 * 16) ^ ((row & 7) << 4);
                    short8 ef = *(const short8*)(sE + (size_t)row * 256 + bc);
                    #pragma unroll
                    for (int cb = 0; cb < 2; cb++)
                        cs_i[m][cb] = __builtin_amdgcn_mfma_f32_16x16x32_bf16(
                            ef, hf_j[kk][cb], cs_i[m][cb], 0, 0, 0);
                }
            }
        }

        // ---- j-side (off-diag): E^T rows=j -> cs_j (this wave: i in wr-half only) ----
        if (!diag) {
            __syncthreads();   // all E reads + spos atomics done before E^T overwrite

            f32x4 cs_j[4][2];
            #pragma unroll
            for (int m = 0; m < 4; m++)
                #pragma unroll
                for (int cb = 0; cb < 2; cb++)
                    cs_j[m][cb] = (f32x4){0.f, 0.f, 0.f, 0.f};

            #pragma unroll
            for (int copy = 0; copy < 2; copy++) {
                #pragma unroll
                for (int m = 0; m < 4; m++) {
                    const int colb = (wr * 64 + m * 16 + l15) * 2;   // i as byte col
                    #pragma unroll
                    for (int n = 0; n < 4; n++) {
                        unsigned short b[4];
                        #pragma unroll
                        for (int q = 0; q < 4; q++) {
                            float e = acc[m][n][q];
                            unsigned short h = f2bf(e);
                            b[q] = copy == 0 ? h : f2bf(e - bf2f(h));
                        }
                        #pragma unroll
                        for (int q = 0; q < 4; q++) {
                            const int row = wc * 64 + n * 16 + l4 * 4 + q;   // j as row
                            *(unsigned short*)(sE + (size_t)row * 256 + (colb ^ ((row & 7) << 4))) = b[q];
                        }
                    }
                }
                #pragma unroll
                for (int m2 = 0; m2 < 4; m2++) {
                    const int row = wc * 64 + m2 * 16 + l15;
                    #pragma unroll
                    for (int kk = 0; kk < 2; kk++) {
                        const int bc = (wr * 128 + kk * 64 + l4 * 16) ^ ((row & 7) << 4);
                        short8 ef = *(const short8*)(sE + (size_t)row * 256 + bc);
                        #pragma unroll
                        for (int cb = 0; cb < 2; cb++)
                            cs_j[m2][cb] = __builtin_amdgcn_mfma_f32_16x16x32_bf16(
                                ef, hf_i[kk][cb], cs_j[m2][cb], 0, 0, 0);
                    }
                }
            }

            // cross-wr combine: wr==1 writes scr, wr==0 adds and dumps fp16
            __syncthreads();
            if (wr == 1) {
                #pragma unroll
                for (int m2 = 0; m2 < 4; m2++)
                    #pragma unroll
                    for (int cb = 0; cb < 2; cb++)
                        #pragma unroll
                        for (int q = 0; q < 4; q++)
                            scr[(wc * 64 + m2 * 16 + l4 * 4 + q) * 33 + cb * 16 + l15] =
                                cs_j[m2][cb][q];
            }
            __syncthreads();
            if (wr == 0) {
                const size_t jsb = (size_t)(it_t * 33 + d) * 2048;   // 128*16 uints/slot
                #pragma unroll
                for (int m2 = 0; m2 < 4; m2++)
                    #pragma unroll
                    for (int q = 0; q < 4; q++) {
                        const int row = wc * 64 + m2 * 16 + l4 * 4 + q;
                        float v0 = cs_j[m2][0][q] + scr[row * 33 + l15];
                        float v1 = cs_j[m2][1][q] + scr[row * 33 + 16 + l15];
                        __half h0 = __float2half_rn(v0 * SCJ);
                        __half h1 = __float2half_rn(v1 * SCJ);
                        unsigned short u0, u1;
                        memcpy(&u0, &h0, 2); memcpy(&u1, &h1, 2);
                        jpart[jsb + (size_t)row * 16 + l15] = (unsigned)u0 | ((unsigned)u1 << 16);
                    }
            }
            if (t < 128) jpos[(size_t)(it_t * 33 + d) * 128 + t] = spos_j[t];
        }

        // ---- d32 blocks: per-tile i-side cross-wc combine + dump + clear ----
        if (!isStrip) {
            __syncthreads();
            if (wc == 1) {
                #pragma unroll
                for (int m = 0; m < 4; m++)
                    #pragma unroll
                    for (int cb = 0; cb < 2; cb++)
                        #pragma unroll
                        for (int q = 0; q < 4; q++)
                            scr[(wr * 64 + m * 16 + l4 * 4 + q) * 33 + cb * 16 + l15] =
                                cs_i[m][cb][q];
            }
            __syncthreads();
            if (wc == 0) {
                const size_t ib = (size_t)(512 + it_t) * 4096;
                #pragma unroll
                for (int m = 0; m < 4; m++)
                    #pragma unroll
                    for (int cb = 0; cb < 2; cb++)
                        #pragma unroll
                        for (int q = 0; q < 4; q++) {
                            const int row = wr * 64 + m * 16 + l4 * 4 + q;
                            ipart[ib + (size_t)row * 32 + cb * 16 + l15] =
                                cs_i[m][cb][q] + scr[row * 33 + cb * 16 + l15];
                        }
            }
            #pragma unroll
            for (int m = 0; m < 4; m++)
                #pragma unroll
                for (int cb = 0; cb < 2; cb++)
                    cs_i[m][cb] = (f32x4){0.f, 0.f, 0.f, 0.f};
            if (t < 128) { ipos[(size_t)(512 + it_t) * 128 + t] = spos_i[t]; spos_i[t] = 0.0f; }
        }
        __syncthreads();   // slab/spos/sE/scr protected before next tile's STAGE
    }

    // ---- strip block end: cross-wc combine + one i-side dump ----
    if (isStrip) {
        float* scr = (float*)&sbuf[0][0][0];
        if (wc == 1) {
            #pragma unroll
            for (int m = 0; m < 4; m++)
                #pragma unroll
                for (int cb = 0; cb < 2; cb++)
                    #pragma unroll
                    for (int q = 0; q < 4; q++)
                        scr[(wr * 64 + m * 16 + l4 * 4 + q) * 33 + cb * 16 + l15] =
                            cs_i[m][cb][q];
        }
        __syncthreads();
        if (wc == 0) {
            const size_t ib = (size_t)swz * 4096;
            #pragma unroll
            for (int m = 0; m < 4; m++)
                #pragma unroll
                for (int cb = 0; cb < 2; cb++)
                    #pragma unroll
                    for (int q = 0; q < 4; q++) {
                        const int row = wr * 64 + m * 16 + l4 * 4 + q;
                        ipart[ib + (size_t)row * 32 + cb * 16 + l15] =
                            cs_i[m][cb][q] + scr[row * 33 + cb * 16 + l15];
                    }
        }
        if (t < 128) ipos[(size_t)swz * 128 + t] = spos_i[t];
    }
}

// ---------------- kernel 4: gather partials + per-anchor loss (8 lanes/anchor) ----------------
__global__ void reduce_kernel(const float* __restrict__ ipart, const unsigned int* __restrict__ jpart,
                              const float* __restrict__ ipos, const float* __restrict__ jpos,
                              const int* __restrict__ counts, const int* __restrict__ labels,
                              float* __restrict__ loss_i, float* __restrict__ validf) {
    int tid = blockIdx.x * blockDim.x + threadIdx.x;
    int i  = tid >> 3;
    int cq = tid & 7;
    if (i >= B_SZ) return;
    const int p = i >> 7, r = i & 127;

    f32x4 ci = (f32x4){0.f, 0.f, 0.f, 0.f};
    #pragma unroll
    for (int s = 0; s < 8; s++)
        ci += *(const f32x4*)&ipart[(size_t)(p * 8 + s) * 4096 + r * 32 + cq * 4];
    if (p < 32)
        ci += *(const f32x4*)&ipart[(size_t)(512 + p) * 4096 + r * 32 + cq * 4];

    f32x4 cj = (f32x4){0.f, 0.f, 0.f, 0.f};
    #pragma unroll 1
    for (int d = 1; d <= 32; d++) {
        if (d == 32 && p < 32) continue;
        const int slot = ((p - d) & 63) * 33 + d;
        uint4 U = *(const uint4*)&jpart[(size_t)slot * 2048 + r * 16 + (cq & 3) * 4];
        const unsigned* up = (const unsigned*)&U;
        #pragma unroll
        for (int e = 0; e < 4; e++) {
            unsigned short hu = (cq < 4) ? (unsigned short)(up[e] & 0xffff)
                                         : (unsigned short)(up[e] >> 16);
            __half hh; memcpy(&hh, &hu, 2);
            cj[e] += __half2float(hh);
        }
    }

    int labi = labels[i];
    float dpart = 0.0f;
    #pragma unroll
    for (int e = 0; e < 4; e++) {
        int c = cq * 4 + e;
        int cnt = counts[c] - (c == labi ? 1 : 0);
        float v = ci[e] + cj[e] * SCJ_INV;
        if (cnt > 0) dpart += v / (float)cnt;
    }
    #pragma unroll
    for (int off = 1; off < 8; off <<= 1) dpart += __shfl_xor(dpart, off, 64);

    if (cq == 0) {
        float psum = 0.0f;
        #pragma unroll
        for (int s = 0; s < 8; s++) psum += ipos[(size_t)(p * 8 + s) * 128 + r];
        if (p < 32) psum += ipos[(size_t)(512 + p) * 128 + r];
        #pragma unroll 1
        for (int d = 1; d <= 32; d++) {
            if (d == 32 && p < 32) continue;
            psum += jpos[(size_t)(((p - d) & 63) * 33 + d) * 128 + r];
        }
        int P = counts[labi] - 1;
        bool valid = P > 0;
        float li = 0.0f;
        if (valid) li = logf(fmaxf(dpart, 1e-30f)) - psum / (float)max(P, 1);
        loss_i[i] = li;
        validf[i] = valid ? 1.0f : 0.0f;
    }
}

// ---------------- kernel 5: deterministic final reduction ----------------
__global__ void final_kernel(const float* __restrict__ loss_i, const float* __restrict__ validf,
                             float* __restrict__ out) {
    __shared__ float ssum[256];
    __shared__ float scnt[256];
    int t = threadIdx.x;
    float s = 0.0f, c = 0.0f;
    for (int i = t; i < B_SZ; i += 256) { s += loss_i[i]; c += validf[i]; }
    ssum[t] = s; scnt[t] = c;
    __syncthreads();
    #pragma unroll
    for (int off = 128; off > 0; off >>= 1) {
        if (t < off) { ssum[t] += ssum[t + off]; scnt[t] += scnt[t + off]; }
        __syncthreads();
    }
    if (t == 0) out[0] = (scnt[0] > 0.0f) ? ssum[0] / scnt[0] : 0.0f;
}

// ---------------- launch ----------------
extern "C" void kernel_launch(void* const* d_in, const int* in_sizes, int n_in,
                              void* d_out, int out_size, void* d_ws, size_t ws_size,
                              hipStream_t stream) {
    const float* feat   = (const float*)d_in[0];
    const int*   labels = (const int*)d_in[1];
    float*       out    = (float*)d_out;

    char* ws = (char*)d_ws;
    size_t off = 0;
    auto alloc = [&](size_t bytes) -> void* {
        void* p = ws + off;
        off = (off + bytes + 255) & ~(size_t)255;
        return p;
    };

    unsigned short* Fhl = (unsigned short*)alloc((size_t)B_SZ * 512 * 2);     // 8.4MB
    int*   counts = (int*)alloc((size_t)NCLS * 4);
    float* loss_i = (float*)alloc((size_t)B_SZ * 4);
    float* validf = (float*)alloc((size_t)B_SZ * 4);
    float*        ipart = (float*)alloc((size_t)544 * 4096 * 4);              // 8.9MB fp32
    unsigned int* jpart = (unsigned int*)alloc((size_t)64 * 33 * 2048 * 4);   // 17.3MB fp16-pairs
    float*        ipos  = (float*)alloc((size_t)544 * 128 * 4);               // 278KB
    float*        jpos  = (float*)alloc((size_t)64 * 33 * 128 * 4);           // 1.1MB

    prep_kernel<<<B_SZ / 4, 256, 0, stream>>>(feat, Fhl);
    count_kernel<<<1, 256, 0, stream>>>(labels, counts);
    sim_kernel<<<NBLK, 256, 0, stream>>>(Fhl, labels, ipart, jpart, ipos, jpos);
    reduce_kernel<<<B_SZ * 8 / 256, 256, 0, stream>>>(ipart, jpart, ipos, jpos,
                                                      counts, labels, loss_i, validf);
    final_kernel<<<1, 256, 0, stream>>>(loss_i, validf, out);
}

// Round 12
// 139.798 us; speedup vs baseline: 2.4430x; 2.4430x over previous
//
#include <hip/hip_runtime.h>
#include <math.h>

#define B_SZ  8192
#define KD    256
#define NCLS  32
#define NCHUNK 8          // j-chunks per i-tile row; grid = 64*NCHUNK = 512 blocks
#define JTPC   8          // 128-wide j-tiles per block
#define SQRT_INVT 3.16227766016838f   // sqrt(10): fold 1/T into normalized rows

typedef __attribute__((ext_vector_type(8))) short short8;
typedef __attribute__((ext_vector_type(4))) float f32x4;

static __device__ __forceinline__ unsigned short f2bf(float f) {
    unsigned u = __float_as_uint(f);
    return (unsigned short)((u + 0x7FFF + ((u >> 16) & 1)) >> 16);   // RNE
}
static __device__ __forceinline__ float bf2f(unsigned short h) {
    return __uint_as_float((unsigned)h << 16);
}

// ---------------- kernel 1: normalize+scale rows, emit combined [hi(256)|lo(256)] bf16 ----------------
__global__ void prep_kernel(const float* __restrict__ feat, unsigned short* __restrict__ Fhl) {
    int row  = blockIdx.x * 4 + (threadIdx.x >> 6);
    int lane = threadIdx.x & 63;
    const float4 v = ((const float4*)(feat + (size_t)row * KD))[lane];
    float s = v.x * v.x + v.y * v.y + v.z * v.z + v.w * v.w;
    #pragma unroll
    for (int off = 1; off < 64; off <<= 1) s += __shfl_xor(s, off, 64);
    float rn = rsqrtf(s) * SQRT_INVT;
    float fn[4] = {v.x * rn, v.y * rn, v.z * rn, v.w * rn};
    ushort4 hi, lo;
    unsigned short* hp = (unsigned short*)&hi;
    unsigned short* lp = (unsigned short*)&lo;
    #pragma unroll
    for (int e = 0; e < 4; e++) {
        unsigned short h = f2bf(fn[e]);
        hp[e] = h;
        lp[e] = f2bf(fn[e] - bf2f(h));
    }
    ((ushort4*)(Fhl + (size_t)row * 512))[lane]       = hi;   // cols 0..255  = hi
    ((ushort4*)(Fhl + (size_t)row * 512 + 256))[lane] = lo;   // cols 256..511 = lo
}

// ---------------- kernel 2: global per-class counts ----------------
__global__ void count_kernel(const int* __restrict__ labels, int* __restrict__ counts) {
    __shared__ int sc[NCLS];
    int t = threadIdx.x;
    if (t < NCLS) sc[t] = 0;
    __syncthreads();
    for (int i = t; i < B_SZ; i += 256) atomicAdd(&sc[labels[i]], 1);
    __syncthreads();
    if (t < NCLS) counts[t] = sc[t];
}

// ---------------- kernel 3: 128x128-tile sim GEMM, 2 blocks/CU + MFMA class reduce ----------------
// 512 blocks (2/CU), 256 threads = 4 waves in 2x2; wave owns 64x64 of C.
// 2-product split: sim = Ahi.Bhi + Ahi.Blo (A-side lo term dropped; eps ~ 2^-9 rel).
// E fed to class-MFMA as bf16-hi only. Next-tile stage0 prefetched under epilogue.
__global__ __launch_bounds__(256, 2) void sim_kernel(
    const unsigned short* __restrict__ Fhl, const int* __restrict__ labels,
    float* __restrict__ pcls, float* __restrict__ ppos)
{
    __shared__ __align__(16) unsigned short sbuf[2][2][128 * 64];  // 64KB: [buf][A/B]
    __shared__ int   slab[128];
    __shared__ float spos[128];

    const int bid = blockIdx.x;
    const int swz = (bid & 7) * 64 + (bid >> 3);   // bijective XCD swizzle (512 % 8 == 0)
    const int itile = swz >> 3;                    // swz / NCHUNK
    const int jc    = swz & 7;                     // swz % NCHUNK
    const int i0    = itile * 128;

    const int t    = threadIdx.x;
    const int wave = t >> 6;
    const int lane = t & 63;
    const int wr   = wave >> 1;      // 0..1 -> 64-row half
    const int wc   = wave & 1;       // 0..1 -> 64-col half
    const int l15  = lane & 15;
    const int l4   = lane >> 4;

    if (t < 128) spos[t] = 0.0f;

    int labi[4];
    #pragma unroll
    for (int m = 0; m < 4; m++) labi[m] = labels[i0 + wr * 64 + m * 16 + l15];

    const int rT = t >> 3;    // row-within-32 staged per quarter
    const int s8 = t & 7;     // physical 16B slot

    auto STAGE = [&](int buf, int j0s, int kc) {
        #pragma unroll
        for (int a = 0; a < 4; ++a) {
            int r   = a * 32 + rT;
            int sl  = s8 ^ (r & 7);                         // logical slot (involution)
            int col = kc + (sl & 3) * 8 + ((sl & 4) << 6);  // slots 0-3 hi, 4-7 lo (+256)
            const unsigned short* gA = Fhl + (size_t)(i0 + r) * 512 + col;
            char* lA = (char*)&sbuf[buf][0][0] + a * 4096 + wave * 1024;
            __builtin_amdgcn_global_load_lds(
                (const __attribute__((address_space(1))) void*)gA,
                (__attribute__((address_space(3))) void*)lA, 16, 0, 0);
            const unsigned short* gB = Fhl + (size_t)(j0s + r) * 512 + col;
            char* lB = (char*)&sbuf[buf][1][0] + a * 4096 + wave * 1024;
            __builtin_amdgcn_global_load_lds(
                (const __attribute__((address_space(1))) void*)gB,
                (__attribute__((address_space(3))) void*)lB, 16, 0, 0);
        }
    };

    // persistent class sums across the block's 8 j-tiles: [m][cb], rows i, cols c
    f32x4 acc_cs[4][2];
    #pragma unroll
    for (int m = 0; m < 4; m++)
        #pragma unroll
        for (int cb = 0; cb < 2; cb++)
            acc_cs[m][cb] = (f32x4){0.f, 0.f, 0.f, 0.f};

    const int jt_beg = jc * JTPC, jt_end = (jc + 1) * JTPC;
    STAGE(0, jt_beg * 128, 0);   // prologue: first tile's k=0

    #pragma unroll 1
    for (int jt = jt_beg; jt < jt_end; ++jt) {
        const int j0 = jt * 128;

        __syncthreads();                    // drains stage0/prefetch; prev epilogue reads done
        if (t < 128) slab[t] = labels[j0 + t];

        f32x4 acc[4][4];
        #pragma unroll
        for (int m = 0; m < 4; m++)
            #pragma unroll
            for (int n = 0; n < 4; n++)
                acc[m][n] = (f32x4){0.f, 0.f, 0.f, 0.f};

        __syncthreads();                    // slab visible (cheap; keeps staging order clean)

        // ---- 2-phase pipelined K-loop: 8 steps of BK=32, 2 products ----
        #pragma unroll 1
        for (int ks = 0; ks < 8; ++ks) {
            if (ks < 7) STAGE((ks + 1) & 1, j0, (ks + 1) * 32);
            const unsigned short* pA = &sbuf[ks & 1][0][0];
            const unsigned short* pB = &sbuf[ks & 1][1][0];
            short8 bh[4], bl[4];
            #pragma unroll
            for (int n = 0; n < 4; ++n) {
                int r = wc * 64 + n * 16 + l15;
                bh[n] = *(const short8*)&pB[r * 64 + ((l4 ^ (r & 7)) * 8)];
                bl[n] = *(const short8*)&pB[r * 64 + (((4 + l4) ^ (r & 7)) * 8)];
            }
            __builtin_amdgcn_s_setprio(1);
            #pragma unroll
            for (int m = 0; m < 4; ++m) {
                int r = wr * 64 + m * 16 + l15;
                short8 ah = *(const short8*)&pA[r * 64 + ((l4 ^ (r & 7)) * 8)];
                #pragma unroll
                for (int n = 0; n < 4; ++n) {
                    // swapped operands: q indexes j. products: BhAh + BlAh (A kept exact via B? no:
                    // C = Ah.(Bh+Bl) -- B-side fully represented, A rounded to bf16)
                    acc[m][n] = __builtin_amdgcn_mfma_f32_16x16x32_bf16(bh[n], ah, acc[m][n], 0, 0, 0);
                    acc[m][n] = __builtin_amdgcn_mfma_f32_16x16x32_bf16(bl[n], ah, acc[m][n], 0, 0, 0);
                }
            }
            __builtin_amdgcn_s_setprio(0);
            __syncthreads();   // drains next stage; swaps buffers
        }

        // ---- prefetch next tile's k=0 into buf0 (free); flies under epilogue ----
        if (jt + 1 < jt_end) STAGE(0, (jt + 1) * 128, 0);

        // ---- epilogue: sim -> spos (rare atomics) + E=exp ----
        #pragma unroll
        for (int m = 0; m < 4; m++) {
            const int il = wr * 64 + m * 16 + l15;
            const int ig = i0 + il;
            #pragma unroll
            for (int n = 0; n < 4; n++) {
                const int jb = wc * 64 + n * 16 + l4 * 4;
                int4 lj = *(const int4*)&slab[jb];
                const int* ljp = (const int*)&lj;
                #pragma unroll
                for (int q = 0; q < 4; q++) {
                    const int jg = j0 + jb + q;
                    float sim = acc[m][n][q];            // already scaled by 1/T
                    bool self = (ig == jg);
                    if (!self && ljp[q] == labi[m]) atomicAdd(&spos[il], sim);
                    acc[m][n][q] = self ? 0.0f : __expf(sim);
                }
            }
        }

        // one-hot B-fragments over this wave's 64 j-cols (2 K=32 slices)
        short8 hf[2][2];
        #pragma unroll
        for (int kk = 0; kk < 2; kk++) {
            const int jb = wc * 64 + kk * 32 + l4 * 8;
            int4 lv0 = *(const int4*)&slab[jb];
            int4 lv1 = *(const int4*)&slab[jb + 4];
            int lv[8] = {lv0.x, lv0.y, lv0.z, lv0.w, lv1.x, lv1.y, lv1.z, lv1.w};
            #pragma unroll
            for (int cb = 0; cb < 2; cb++) {
                short8 h;
                #pragma unroll
                for (int e = 0; e < 8; e++)
                    h[e] = (lv[e] == cb * 16 + l15) ? (short)0x3F80 : (short)0;
                hf[kk][cb] = h;
            }
        }

        char* sE = (char*)&sbuf[1][0][0];   // 32KB: [128 i][256B] bf16-hi E, XOR-swizzled rows

        // single copy: E-hi -> CS MFMA (accumulate into persistent acc_cs)
        #pragma unroll
        for (int m = 0; m < 4; m++) {
            const int row = wr * 64 + m * 16 + l15;
            #pragma unroll
            for (int n = 0; n < 4; n++) {
                const int bc = (wc * 128 + n * 32 + l4 * 8) ^ ((row & 7) << 4);
                uint2 w;
                w.x = (unsigned)f2bf(acc[m][n][0]) | ((unsigned)f2bf(acc[m][n][1]) << 16);
                w.y = (unsigned)f2bf(acc[m][n][2]) | ((unsigned)f2bf(acc[m][n][3]) << 16);
                *(uint2*)(sE + (size_t)row * 256 + bc) = w;
            }
        }
        #pragma unroll
        for (int m = 0; m < 4; m++) {
            const int row = wr * 64 + m * 16 + l15;
            #pragma unroll
            for (int kk = 0; kk < 2; kk++) {
                const int bc = (wc * 128 + kk * 64 + l4 * 16) ^ ((row & 7) << 4);
                short8 ef = *(const short8*)(sE + (size_t)row * 256 + bc);
                #pragma unroll
                for (int cb = 0; cb < 2; cb++)
                    acc_cs[m][cb] = __builtin_amdgcn_mfma_f32_16x16x32_bf16(
                        ef, hf[kk][cb], acc_cs[m][cb], 0, 0, 0);
            }
        }
        // no barrier here: loop-top __syncthreads() protects slab/sE before reuse
    }

    // ---- block end: deterministic cross-wave (wc) reduce, write partials ----
    __syncthreads();
    float* scr = (float*)&sbuf[0][0][0];   // [128][33] f32
    if (wc == 1) {
        #pragma unroll
        for (int m = 0; m < 4; m++)
            #pragma unroll
            for (int cb = 0; cb < 2; cb++)
                #pragma unroll
                for (int q = 0; q < 4; q++)
                    scr[(wr * 64 + m * 16 + l4 * 4 + q) * 33 + cb * 16 + l15] =
                        acc_cs[m][cb][q];
    }
    __syncthreads();
    if (wc == 0) {
        float* pc = pcls + (size_t)(itile * NCHUNK + jc) * 128 * NCLS;
        #pragma unroll
        for (int m = 0; m < 4; m++)
            #pragma unroll
            for (int cb = 0; cb < 2; cb++)
                #pragma unroll
                for (int q = 0; q < 4; q++) {
                    const int r = wr * 64 + m * 16 + l4 * 4 + q;
                    const int c = cb * 16 + l15;
                    pc[r * NCLS + c] = acc_cs[m][cb][q] + scr[r * 33 + c];
                }
    }
    if (t < 128) ppos[(size_t)(itile * NCHUNK + jc) * 128 + t] = spos[t];
}

// ---------------- kernel 4: per-anchor loss (8 lanes per anchor) ----------------
__global__ void reduce_kernel(const float* __restrict__ pcls, const float* __restrict__ ppos,
                              const int* __restrict__ counts, const int* __restrict__ labels,
                              float* __restrict__ loss_i, float* __restrict__ validf) {
    int tid = blockIdx.x * blockDim.x + threadIdx.x;
    int i  = tid >> 3;
    int cq = tid & 7;
    if (i >= B_SZ) return;
    int itile = i >> 7, ilocal = i & 127;

    f32x4 cs = (f32x4){0.f, 0.f, 0.f, 0.f};
    for (int ch = 0; ch < NCHUNK; ch++) {
        const float* p = pcls + ((size_t)(itile * NCHUNK + ch) * 128 + ilocal) * NCLS + cq * 4;
        f32x4 v = *(const f32x4*)p;
        cs = cs + v;
    }
    int labi = labels[i];
    float dpart = 0.0f;
    #pragma unroll
    for (int e = 0; e < 4; e++) {
        int c = cq * 4 + e;
        int cnt = counts[c] - (c == labi ? 1 : 0);
        if (cnt > 0) dpart += cs[e] / (float)cnt;
    }
    #pragma unroll
    for (int off = 1; off < 8; off <<= 1) dpart += __shfl_xor(dpart, off, 64);

    if (cq == 0) {
        float psum = 0.0f;
        for (int ch = 0; ch < NCHUNK; ch++)
            psum += ppos[(size_t)(itile * NCHUNK + ch) * 128 + ilocal];
        int P = counts[labi] - 1;
        bool valid = P > 0;
        float li = 0.0f;
        if (valid) li = logf(fmaxf(dpart, 1e-30f)) - psum / (float)max(P, 1);
        loss_i[i] = li;
        validf[i] = valid ? 1.0f : 0.0f;
    }
}

// ---------------- kernel 5: deterministic final reduction ----------------
__global__ void final_kernel(const float* __restrict__ loss_i, const float* __restrict__ validf,
                             float* __restrict__ out) {
    __shared__ float ssum[256];
    __shared__ float scnt[256];
    int t = threadIdx.x;
    float s = 0.0f, c = 0.0f;
    for (int i = t; i < B_SZ; i += 256) { s += loss_i[i]; c += validf[i]; }
    ssum[t] = s; scnt[t] = c;
    __syncthreads();
    #pragma unroll
    for (int off = 128; off > 0; off >>= 1) {
        if (t < off) { ssum[t] += ssum[t + off]; scnt[t] += scnt[t + off]; }
        __syncthreads();
    }
    if (t == 0) out[0] = (scnt[0] > 0.0f) ? ssum[0] / scnt[0] : 0.0f;
}

// ---------------- launch ----------------
extern "C" void kernel_launch(void* const* d_in, const int* in_sizes, int n_in,
                              void* d_out, int out_size, void* d_ws, size_t ws_size,
                              hipStream_t stream) {
    const float* feat   = (const float*)d_in[0];
    const int*   labels = (const int*)d_in[1];
    float*       out    = (float*)d_out;

    char* ws = (char*)d_ws;
    size_t off = 0;
    auto alloc = [&](size_t bytes) -> void* {
        void* p = ws + off;
        off = (off + bytes + 255) & ~(size_t)255;
        return p;
    };

    unsigned short* Fhl = (unsigned short*)alloc((size_t)B_SZ * 512 * 2);     // 8.4MB
    int*   counts = (int*)alloc((size_t)NCLS * 4);
    float* loss_i = (float*)alloc((size_t)B_SZ * 4);
    float* validf = (float*)alloc((size_t)B_SZ * 4);
    float* ppos   = (float*)alloc((size_t)512 * 128 * 4);                     // 256KB
    float* pcls   = (float*)alloc((size_t)512 * 128 * NCLS * 4);              // 8.4MB

    prep_kernel<<<B_SZ / 4, 256, 0, stream>>>(feat, Fhl);
    count_kernel<<<1, 256, 0, stream>>>(labels, counts);
    sim_kernel<<<512, 256, 0, stream>>>(Fhl, labels, pcls, ppos);
    reduce_kernel<<<B_SZ * 8 / 256, 256, 0, stream>>>(pcls, ppos, counts, labels, loss_i, validf);
    final_kernel<<<1, 256, 0, stream>>>(loss_i, validf, out);
}

// Round 13
// 100.860 us; speedup vs baseline: 3.3862x; 1.3861x over previous
//
#include <hip/hip_runtime.h>
#include <math.h>

#define B_SZ  8192
#define KD    256
#define NCLS  32
#define NCHUNK 8          // j-chunks per i-tile row; grid = 64*NCHUNK = 512 blocks
#define JTPC   8          // 128-wide j-tiles per block
#define SQRT_INVT 3.16227766016838f   // sqrt(10): fold 1/T into normalized rows

typedef __attribute__((ext_vector_type(8))) short short8;
typedef __attribute__((ext_vector_type(4))) float f32x4;

static __device__ __forceinline__ unsigned short f2bf(float f) {
    unsigned u = __float_as_uint(f);
    return (unsigned short)((u + 0x7FFF + ((u >> 16) & 1)) >> 16);   // RNE
}

// ---------------- kernel 1: normalize+scale rows -> bf16 (single precision level) ----------------
__global__ void prep_kernel(const float* __restrict__ feat, unsigned short* __restrict__ Fbf) {
    int row  = blockIdx.x * 4 + (threadIdx.x >> 6);
    int lane = threadIdx.x & 63;
    const float4 v = ((const float4*)(feat + (size_t)row * KD))[lane];
    float s = v.x * v.x + v.y * v.y + v.z * v.z + v.w * v.w;
    #pragma unroll
    for (int off = 1; off < 64; off <<= 1) s += __shfl_xor(s, off, 64);
    float rn = rsqrtf(s) * SQRT_INVT;
    float fn[4] = {v.x * rn, v.y * rn, v.z * rn, v.w * rn};
    ushort4 hi;
    unsigned short* hp = (unsigned short*)&hi;
    #pragma unroll
    for (int e = 0; e < 4; e++) hp[e] = f2bf(fn[e]);
    ((ushort4*)(Fbf + (size_t)row * KD))[lane] = hi;
}

// ---------------- kernel 2: global per-class counts ----------------
__global__ void count_kernel(const int* __restrict__ labels, int* __restrict__ counts) {
    __shared__ int sc[NCLS];
    int t = threadIdx.x;
    if (t < NCLS) sc[t] = 0;
    __syncthreads();
    for (int i = t; i < B_SZ; i += 256) atomicAdd(&sc[labels[i]], 1);
    __syncthreads();
    if (t < NCLS) counts[t] = sc[t];
}

// ---------------- kernel 3: 128x128-tile bf16 sim GEMM (BK=64, 4 K-steps) + MFMA class reduce ----------------
// 512 blocks (2/CU), 256 threads = 4 waves in 2x2; wave owns 64x64 of C.
// Pure bf16 product (scalar-output error ~1e-4 << 0.073 threshold).
__global__ __launch_bounds__(256, 2) void sim_kernel(
    const unsigned short* __restrict__ Fbf, const int* __restrict__ labels,
    float* __restrict__ pcls, float* __restrict__ ppos)
{
    __shared__ __align__(16) unsigned short sbuf[2][2][128 * 64];  // 64KB: [buf][A/B], 64 shorts = K=64/row
    __shared__ int   slab[128];
    __shared__ float spos[128];

    const int bid = blockIdx.x;
    const int swz = (bid & 7) * 64 + (bid >> 3);   // bijective XCD swizzle (512 % 8 == 0)
    const int itile = swz >> 3;                    // swz / NCHUNK
    const int jc    = swz & 7;                     // swz % NCHUNK
    const int i0    = itile * 128;

    const int t    = threadIdx.x;
    const int wave = t >> 6;
    const int lane = t & 63;
    const int wr   = wave >> 1;      // 0..1 -> 64-row half
    const int wc   = wave & 1;       // 0..1 -> 64-col half
    const int l15  = lane & 15;
    const int l4   = lane >> 4;

    if (t < 128) spos[t] = 0.0f;

    int labi[4];
    #pragma unroll
    for (int m = 0; m < 4; m++) labi[m] = labels[i0 + wr * 64 + m * 16 + l15];

    const int rT = t >> 3;    // row-within-32 staged per quarter
    const int s8 = t & 7;     // physical 16B slot

    auto STAGE = [&](int buf, int j0s, int kc) {
        #pragma unroll
        for (int a = 0; a < 4; ++a) {
            int r   = a * 32 + rT;
            int sl  = s8 ^ (r & 7);          // logical k-slot (involution)
            int col = kc + sl * 8;           // 8 shorts per slot
            const unsigned short* gA = Fbf + (size_t)(i0 + r) * KD + col;
            char* lA = (char*)&sbuf[buf][0][0] + a * 4096 + wave * 1024;
            __builtin_amdgcn_global_load_lds(
                (const __attribute__((address_space(1))) void*)gA,
                (__attribute__((address_space(3))) void*)lA, 16, 0, 0);
            const unsigned short* gB = Fbf + (size_t)(j0s + r) * KD + col;
            char* lB = (char*)&sbuf[buf][1][0] + a * 4096 + wave * 1024;
            __builtin_amdgcn_global_load_lds(
                (const __attribute__((address_space(1))) void*)gB,
                (__attribute__((address_space(3))) void*)lB, 16, 0, 0);
        }
    };

    // persistent class sums across the block's 8 j-tiles: [m][cb], rows i, cols c
    f32x4 acc_cs[4][2];
    #pragma unroll
    for (int m = 0; m < 4; m++)
        #pragma unroll
        for (int cb = 0; cb < 2; cb++)
            acc_cs[m][cb] = (f32x4){0.f, 0.f, 0.f, 0.f};

    const int jt_beg = jc * JTPC, jt_end = (jc + 1) * JTPC;
    STAGE(0, jt_beg * 128, 0);   // prologue: first tile's k=0

    #pragma unroll 1
    for (int jt = jt_beg; jt < jt_end; ++jt) {
        const int j0 = jt * 128;

        __syncthreads();                    // drains stage0/prefetch; prev epilogue reads done
        if (t < 128) slab[t] = labels[j0 + t];

        f32x4 acc[4][4];
        #pragma unroll
        for (int m = 0; m < 4; m++)
            #pragma unroll
            for (int n = 0; n < 4; n++)
                acc[m][n] = (f32x4){0.f, 0.f, 0.f, 0.f};

        __syncthreads();                    // slab visible

        // ---- 2-phase pipelined K-loop: 4 steps of BK=64 ----
        #pragma unroll 1
        for (int ks = 0; ks < 4; ++ks) {
            if (ks < 3) STAGE((ks + 1) & 1, j0, (ks + 1) * 64);
            const unsigned short* pA = &sbuf[ks & 1][0][0];
            const unsigned short* pB = &sbuf[ks & 1][1][0];
            short8 bf4[4][2];
            #pragma unroll
            for (int n = 0; n < 4; ++n) {
                int r = wc * 64 + n * 16 + l15;
                #pragma unroll
                for (int kk = 0; kk < 2; ++kk)
                    bf4[n][kk] = *(const short8*)&pB[r * 64 + (((kk * 4 + l4) ^ (r & 7)) * 8)];
            }
            __builtin_amdgcn_s_setprio(1);
            #pragma unroll
            for (int m = 0; m < 4; ++m) {
                int r = wr * 64 + m * 16 + l15;
                short8 a0 = *(const short8*)&pA[r * 64 + ((l4 ^ (r & 7)) * 8)];
                short8 a1 = *(const short8*)&pA[r * 64 + (((4 + l4) ^ (r & 7)) * 8)];
                #pragma unroll
                for (int n = 0; n < 4; ++n) {
                    // swapped operands: q indexes j
                    acc[m][n] = __builtin_amdgcn_mfma_f32_16x16x32_bf16(bf4[n][0], a0, acc[m][n], 0, 0, 0);
                    acc[m][n] = __builtin_amdgcn_mfma_f32_16x16x32_bf16(bf4[n][1], a1, acc[m][n], 0, 0, 0);
                }
            }
            __builtin_amdgcn_s_setprio(0);
            __syncthreads();   // drains next stage; swaps buffers
        }

        // ---- prefetch next tile's k=0 into buf0 (free); flies under epilogue ----
        if (jt + 1 < jt_end) STAGE(0, (jt + 1) * 128, 0);

        // ---- epilogue: sim -> spos (rare atomics) + E=exp ----
        #pragma unroll
        for (int m = 0; m < 4; m++) {
            const int il = wr * 64 + m * 16 + l15;
            const int ig = i0 + il;
            #pragma unroll
            for (int n = 0; n < 4; n++) {
                const int jb = wc * 64 + n * 16 + l4 * 4;
                int4 lj = *(const int4*)&slab[jb];
                const int* ljp = (const int*)&lj;
                #pragma unroll
                for (int q = 0; q < 4; q++) {
                    const int jg = j0 + jb + q;
                    float sim = acc[m][n][q];            // already scaled by 1/T
                    bool self = (ig == jg);
                    if (!self && ljp[q] == labi[m]) atomicAdd(&spos[il], sim);
                    acc[m][n][q] = self ? 0.0f : __expf(sim);
                }
            }
        }

        // one-hot B-fragments over this wave's 64 j-cols (2 K=32 slices)
        short8 hf[2][2];
        #pragma unroll
        for (int kk = 0; kk < 2; kk++) {
            const int jb = wc * 64 + kk * 32 + l4 * 8;
            int4 lv0 = *(const int4*)&slab[jb];
            int4 lv1 = *(const int4*)&slab[jb + 4];
            int lv[8] = {lv0.x, lv0.y, lv0.z, lv0.w, lv1.x, lv1.y, lv1.z, lv1.w};
            #pragma unroll
            for (int cb = 0; cb < 2; cb++) {
                short8 h;
                #pragma unroll
                for (int e = 0; e < 8; e++)
                    h[e] = (lv[e] == cb * 16 + l15) ? (short)0x3F80 : (short)0;
                hf[kk][cb] = h;
            }
        }

        char* sE = (char*)&sbuf[1][0][0];   // 32KB: [128 i][256B] bf16 E, XOR-swizzled rows

        // E-hi -> CS MFMA (accumulate into persistent acc_cs)
        #pragma unroll
        for (int m = 0; m < 4; m++) {
            const int row = wr * 64 + m * 16 + l15;
            #pragma unroll
            for (int n = 0; n < 4; n++) {
                const int bc = (wc * 128 + n * 32 + l4 * 8) ^ ((row & 7) << 4);
                uint2 w;
                w.x = (unsigned)f2bf(acc[m][n][0]) | ((unsigned)f2bf(acc[m][n][1]) << 16);
                w.y = (unsigned)f2bf(acc[m][n][2]) | ((unsigned)f2bf(acc[m][n][3]) << 16);
                *(uint2*)(sE + (size_t)row * 256 + bc) = w;
            }
        }
        #pragma unroll
        for (int m = 0; m < 4; m++) {
            const int row = wr * 64 + m * 16 + l15;
            #pragma unroll
            for (int kk = 0; kk < 2; kk++) {
                const int bc = (wc * 128 + kk * 64 + l4 * 16) ^ ((row & 7) << 4);
                short8 ef = *(const short8*)(sE + (size_t)row * 256 + bc);
                #pragma unroll
                for (int cb = 0; cb < 2; cb++)
                    acc_cs[m][cb] = __builtin_amdgcn_mfma_f32_16x16x32_bf16(
                        ef, hf[kk][cb], acc_cs[m][cb], 0, 0, 0);
            }
        }
        // no barrier here: loop-top __syncthreads() protects slab/sE before reuse
    }

    // ---- block end: deterministic cross-wave (wc) reduce, write partials ----
    __syncthreads();
    float* scr = (float*)&sbuf[0][0][0];   // [128][33] f32
    if (wc == 1) {
        #pragma unroll
        for (int m = 0; m < 4; m++)
            #pragma unroll
            for (int cb = 0; cb < 2; cb++)
                #pragma unroll
                for (int q = 0; q < 4; q++)
                    scr[(wr * 64 + m * 16 + l4 * 4 + q) * 33 + cb * 16 + l15] =
                        acc_cs[m][cb][q];
    }
    __syncthreads();
    if (wc == 0) {
        float* pc = pcls + (size_t)(itile * NCHUNK + jc) * 128 * NCLS;
        #pragma unroll
        for (int m = 0; m < 4; m++)
            #pragma unroll
            for (int cb = 0; cb < 2; cb++)
                #pragma unroll
                for (int q = 0; q < 4; q++) {
                    const int r = wr * 64 + m * 16 + l4 * 4 + q;
                    const int c = cb * 16 + l15;
                    pc[r * NCLS + c] = acc_cs[m][cb][q] + scr[r * 33 + c];
                }
    }
    if (t < 128) ppos[(size_t)(itile * NCHUNK + jc) * 128 + t] = spos[t];
}

// ---------------- kernel 4: per-anchor loss (8 lanes per anchor) ----------------
__global__ void reduce_kernel(const float* __restrict__ pcls, const float* __restrict__ ppos,
                              const int* __restrict__ counts, const int* __restrict__ labels,
                              float* __restrict__ loss_i, float* __restrict__ validf) {
    int tid = blockIdx.x * blockDim.x + threadIdx.x;
    int i  = tid >> 3;
    int cq = tid & 7;
    if (i >= B_SZ) return;
    int itile = i >> 7, ilocal = i & 127;

    f32x4 cs = (f32x4){0.f, 0.f, 0.f, 0.f};
    for (int ch = 0; ch < NCHUNK; ch++) {
        const float* p = pcls + ((size_t)(itile * NCHUNK + ch) * 128 + ilocal) * NCLS + cq * 4;
        f32x4 v = *(const f32x4*)p;
        cs = cs + v;
    }
    int labi = labels[i];
    float dpart = 0.0f;
    #pragma unroll
    for (int e = 0; e < 4; e++) {
        int c = cq * 4 + e;
        int cnt = counts[c] - (c == labi ? 1 : 0);
        if (cnt > 0) dpart += cs[e] / (float)cnt;
    }
    #pragma unroll
    for (int off = 1; off < 8; off <<= 1) dpart += __shfl_xor(dpart, off, 64);

    if (cq == 0) {
        float psum = 0.0f;
        for (int ch = 0; ch < NCHUNK; ch++)
            psum += ppos[(size_t)(itile * NCHUNK + ch) * 128 + ilocal];
        int P = counts[labi] - 1;
        bool valid = P > 0;
        float li = 0.0f;
        if (valid) li = logf(fmaxf(dpart, 1e-30f)) - psum / (float)max(P, 1);
        loss_i[i] = li;
        validf[i] = valid ? 1.0f : 0.0f;
    }
}

// ---------------- kernel 5: deterministic final reduction ----------------
__global__ void final_kernel(const float* __restrict__ loss_i, const float* __restrict__ validf,
                             float* __restrict__ out) {
    __shared__ float ssum[256];
    __shared__ float scnt[256];
    int t = threadIdx.x;
    float s = 0.0f, c = 0.0f;
    for (int i = t; i < B_SZ; i += 256) { s += loss_i[i]; c += validf[i]; }
    ssum[t] = s; scnt[t] = c;
    __syncthreads();
    #pragma unroll
    for (int off = 128; off > 0; off >>= 1) {
        if (t < off) { ssum[t] += ssum[t + off]; scnt[t] += scnt[t + off]; }
        __syncthreads();
    }
    if (t == 0) out[0] = (scnt[0] > 0.0f) ? ssum[0] / scnt[0] : 0.0f;
}

// ---------------- launch ----------------
extern "C" void kernel_launch(void* const* d_in, const int* in_sizes, int n_in,
                              void* d_out, int out_size, void* d_ws, size_t ws_size,
                              hipStream_t stream) {
    const float* feat   = (const float*)d_in[0];
    const int*   labels = (const int*)d_in[1];
    float*       out    = (float*)d_out;

    char* ws = (char*)d_ws;
    size_t off = 0;
    auto alloc = [&](size_t bytes) -> void* {
        void* p = ws + off;
        off = (off + bytes + 255) & ~(size_t)255;
        return p;
    };

    unsigned short* Fbf = (unsigned short*)alloc((size_t)B_SZ * KD * 2);      // 4.2MB
    int*   counts = (int*)alloc((size_t)NCLS * 4);
    float* loss_i = (float*)alloc((size_t)B_SZ * 4);
    float* validf = (float*)alloc((size_t)B_SZ * 4);
    float* ppos   = (float*)alloc((size_t)512 * 128 * 4);                     // 256KB
    float* pcls   = (float*)alloc((size_t)512 * 128 * NCLS * 4);              // 8.4MB

    prep_kernel<<<B_SZ / 4, 256, 0, stream>>>(feat, Fbf);
    count_kernel<<<1, 256, 0, stream>>>(labels, counts);
    sim_kernel<<<512, 256, 0, stream>>>(Fbf, labels, pcls, ppos);
    reduce_kernel<<<B_SZ * 8 / 256, 256, 0, stream>>>(pcls, ppos, counts, labels, loss_i, validf);
    final_kernel<<<1, 256, 0, stream>>>(loss_i, validf, out);
}